// Round 6
// baseline (902.792 us; speedup 1.0000x reference)
//
#include <hip/hip_runtime.h>

#define T_STEPS 256
#define BATCH   2048
#define HID     128
#define ROWS    8          // batch rows per block (grid = BATCH/ROWS = 256)

typedef short short8  __attribute__((ext_vector_type(8)));
typedef float float4v __attribute__((ext_vector_type(4)));
typedef unsigned int uint4v __attribute__((ext_vector_type(4)));

__device__ __forceinline__ unsigned short f2bf(float f) {
    unsigned int u = __builtin_bit_cast(unsigned int, f);
    u += 0x7fffu + ((u >> 16) & 1u);
    return (unsigned short)(u >> 16);
}
__device__ __forceinline__ float bf2f(unsigned short b) {
    unsigned int u = ((unsigned int)b) << 16;
    return __builtin_bit_cast(float, u);
}

#if __has_builtin(__builtin_amdgcn_exp2f)
#define EXP2F(x) __builtin_amdgcn_exp2f(x)
#else
#define EXP2F(x) exp2f(x)
#endif
__device__ __forceinline__ float sigf(float x) {
    return __builtin_amdgcn_rcpf(1.0f + EXP2F(x * -1.442695041f));
}
__device__ __forceinline__ float tanh_fast(float x) {
    return 2.0f * __builtin_amdgcn_rcpf(1.0f + EXP2F(x * -2.885390082f)) - 1.0f;
}

// Raw barrier without the vmcnt(0) drain of __syncthreads().
__device__ __forceinline__ void block_sync_lds() {
    asm volatile("s_waitcnt lgkmcnt(0)" ::: "memory");
    __builtin_amdgcn_s_barrier();
    __builtin_amdgcn_sched_barrier(0);
}

// LDS addr in one 2 KB buffer: h[8 rows][256 B], XOR-swizzled (G4).
__device__ __forceinline__ int lposR(int row, int byteoff) {
    return (row * 256 + byteoff) ^ ((row & 7) << 4);
}

__device__ __forceinline__ short8 load_w8(const float* __restrict__ p) {
    float4v a = *reinterpret_cast<const float4v*>(p);
    float4v b = *reinterpret_cast<const float4v*>(p + 4);
    short8 r;
    r[0] = (short)f2bf(a[0]); r[1] = (short)f2bf(a[1]);
    r[2] = (short)f2bf(a[2]); r[3] = (short)f2bf(a[3]);
    r[4] = (short)f2bf(b[0]); r[5] = (short)f2bf(b[1]);
    r[6] = (short)f2bf(b[2]); r[7] = (short)f2bf(b[3]);
    return r;
}

// One LSTM layer. Block = 512 thr (8 waves), 8 batch rows, grid 256 (1/CU).
// h-exchange via LDS (2x2KB ping-pong, 1 raw barrier/step). x-fragments are
// loaded DIRECTLY from global into MFMA operand registers with 1-step
// prefetch (no LDS round-trip; K-pad columns killed by zero weights).
// A-tile rows 8-15 alias rows 0-7 (LDS broadcast); upper lanes consume acc
// regs {2,3}, lower {0,1} -> 2 lane-local cell updates/thread.
template<bool IS_L0, bool WRITE_H, bool FINAL>
__global__ __launch_bounds__(512, 2)
void lstm_layer(const float* __restrict__ x0,
                const float* __restrict__ Wih,
                const float* __restrict__ Whh,
                const float* __restrict__ bih,
                const float* __restrict__ bhh,
                unsigned short* __restrict__ hbuf,   // [T][B][H] bf16
                const float* __restrict__ Wfc,
                const float* __restrict__ bfc,
                float* __restrict__ out)
{
    constexpr int KS_X  = IS_L0 ? 1 : 4;             // x K-slices (reg-fed)
    constexpr int BUF   = ROWS * 256;                // 2048 B per buffer
    __shared__ __attribute__((aligned(16))) unsigned char a_lds[2 * BUF];

    const int tid   = threadIdx.x;
    const int lane  = tid & 63;
    const int wv    = tid >> 6;
    const int b0    = blockIdx.x * ROWS;

    const int t16   = lane & 15;
    const int kgrp8 = (lane >> 4) * 8;
    const int jcol  = 16 * wv + t16;                 // owned gate/h column
    const int arow  = t16 & 7;                       // aliased A row
    const bool upper = (lane >= 32);
    const int row0   = (((lane >> 4) * 4) & 7) + (upper ? 2 : 0);

    // h-fragment LDS offsets (within one buffer)
    int aoff[4];
    #pragma unroll
    for (int ks = 0; ks < 4; ++ks)
        aoff[ks] = lposR(arow, ks * 64 + kgrp8 * 2);
    const int hwoff0 = lposR(row0,     2 * jcol);
    const int hwoff1 = lposR(row0 + 1, 2 * jcol);

    // h global-write map: 512 threads x 4 B cover 8 rows x 256 B
    const int srow4 = tid >> 6, scol4 = tid & 63;
    const int hroff4 = lposR(srow4, scol4 * 4);
    const size_t sgoff4 = (size_t)(b0 + srow4) * HID + scol4 * 2;   // shorts

    // x direct-load addresses
    // L1/L2: hbuf[t][b0+arow][s*32+kgrp8 .. +8]  (16 B bf16)
    size_t xgo[4];
    #pragma unroll
    for (int s = 0; s < 4; ++s)
        xgo[s] = (size_t)(b0 + arow) * HID + s * 32 + kgrp8;
    // L0: x0[b0+arow][t][kgrp8 .. +8] fp32 (clamped for pad lanes; zero weights
    // make the loaded values irrelevant there)
    const bool xok = (kgrp8 < 24);
    const size_t x0goff = (size_t)(b0 + arow) * (T_STEPS * 24) + (xok ? kgrp8 : 0);

    // ---- weights -> registers ----
    short8 wf[4][4 + KS_X];
    float  bias[4];
    #pragma unroll
    for (int q = 0; q < 4; ++q) {
        const int n = 128 * q + jcol;
        bias[q] = bih[n] + bhh[n];
        #pragma unroll
        for (int ks = 0; ks < 4; ++ks)
            wf[q][ks] = load_w8(Whh + n * 128 + ks * 32 + kgrp8);
        if (IS_L0) {
            if (xok) wf[q][4] = load_w8(Wih + n * 24 + kgrp8);
            else     { short8 z = {0,0,0,0,0,0,0,0}; wf[q][4] = z; }
        } else {
            #pragma unroll
            for (int s = 0; s < 4; ++s)
                wf[q][4 + s] = load_w8(Wih + n * 128 + s * 32 + kgrp8);
        }
    }

    // zero both h buffers (h(-1)=0): 512 thr x 8 B = 4 KB
    {
        int2 z = {0, 0};
        *reinterpret_cast<int2*>(&a_lds[tid * 8]) = z;
    }
    __syncthreads();

    // x prefetch registers (double-buffered across steps)
    short8  xhA[4], xhB[4];      // used when !IS_L0
    float4v xfA[2], xfB[2];      // used when IS_L0
    if (!IS_L0) {
        #pragma unroll
        for (int s = 0; s < 4; ++s)
            xhA[s] = *reinterpret_cast<const short8*>(&hbuf[xgo[s]]);   // t=0
    } else {
        const float* p = x0 + x0goff;                                    // t=0
        xfA[0] = *reinterpret_cast<const float4v*>(p);
        xfA[1] = *reinterpret_cast<const float4v*>(p + 4);
    }

    float creg[2] = {0.f, 0.f};

    auto step = [&](int t, int rb, int wb,
                    short8 (&xhc)[4], short8 (&xhn)[4],
                    float4v (&xfc)[2], float4v (&xfn)[2]) {
        // A: global write of h(t-1) from read buffer (overlaps compute)
        if (WRITE_H && t > 0) {
            unsigned int hv = *reinterpret_cast<const unsigned int*>(&a_lds[rb + hroff4]);
            *reinterpret_cast<unsigned int*>(
                &hbuf[(size_t)(t - 1) * (BATCH * HID) + sgoff4]) = hv;
        }
        // B: issue x(t+1) loads into the "next" registers
        if (t + 1 < T_STEPS) {
            if constexpr (IS_L0) {
                const float* p = x0 + x0goff + (size_t)(t + 1) * 24;
                xfn[0] = *reinterpret_cast<const float4v*>(p);
                xfn[1] = *reinterpret_cast<const float4v*>(p + 4);
            } else {
                #pragma unroll
                for (int s = 0; s < 4; ++s)
                    xhn[s] = *reinterpret_cast<const short8*>(
                        &hbuf[(size_t)(t + 1) * (BATCH * HID) + xgo[s]]);
            }
        }
        // D: MFMA. Issue h ds_reads, then x-MFMAs (reg operands) cover latency.
        short8 hva[4];
        #pragma unroll
        for (int ks = 0; ks < 4; ++ks)
            hva[ks] = *reinterpret_cast<const short8*>(&a_lds[rb + aoff[ks]]);
        float4v acc[4];
        #pragma unroll
        for (int q = 0; q < 4; ++q)
            acc[q] = float4v{bias[q], bias[q], bias[q], bias[q]};
        __builtin_amdgcn_s_setprio(1);
        if constexpr (IS_L0) {
            unsigned int u0, u1, u2, u3;
            asm("v_cvt_pk_bf16_f32 %0, %1, %2" : "=v"(u0) : "v"(xfc[0][0]), "v"(xfc[0][1]));
            asm("v_cvt_pk_bf16_f32 %0, %1, %2" : "=v"(u1) : "v"(xfc[0][2]), "v"(xfc[0][3]));
            asm("v_cvt_pk_bf16_f32 %0, %1, %2" : "=v"(u2) : "v"(xfc[1][0]), "v"(xfc[1][1]));
            asm("v_cvt_pk_bf16_f32 %0, %1, %2" : "=v"(u3) : "v"(xfc[1][2]), "v"(xfc[1][3]));
            uint4v xu = {u0, u1, u2, u3};
            short8 av = __builtin_bit_cast(short8, xu);
            #pragma unroll
            for (int q = 0; q < 4; ++q)
                acc[q] = __builtin_amdgcn_mfma_f32_16x16x32_bf16(av, wf[q][4], acc[q], 0, 0, 0);
        } else {
            #pragma unroll
            for (int s = 0; s < 4; ++s)
                #pragma unroll
                for (int q = 0; q < 4; ++q)
                    acc[q] = __builtin_amdgcn_mfma_f32_16x16x32_bf16(xhc[s], wf[q][4 + s], acc[q], 0, 0, 0);
        }
        #pragma unroll
        for (int ks = 0; ks < 4; ++ks)
            #pragma unroll
            for (int q = 0; q < 4; ++q)
                acc[q] = __builtin_amdgcn_mfma_f32_16x16x32_bf16(hva[ks], wf[q][ks], acc[q], 0, 0, 0);
        __builtin_amdgcn_s_setprio(0);
        // E: 2 lane-local cell updates/thread
        float g0[4], g1[4];
        #pragma unroll
        for (int q = 0; q < 4; ++q) {
            g0[q] = upper ? acc[q][2] : acc[q][0];
            g1[q] = upper ? acc[q][3] : acc[q][1];
        }
        const float c0 = sigf(g0[1]) * creg[0] + sigf(g0[0]) * tanh_fast(g0[2]);
        const float c1 = sigf(g1[1]) * creg[1] + sigf(g1[0]) * tanh_fast(g1[2]);
        creg[0] = c0;  creg[1] = c1;
        const float h0 = sigf(g0[3]) * tanh_fast(c0);
        const float h1 = sigf(g1[3]) * tanh_fast(c1);
        unsigned int packed;
        asm("v_cvt_pk_bf16_f32 %0, %1, %2" : "=v"(packed) : "v"(h0), "v"(h1));
        *reinterpret_cast<unsigned short*>(&a_lds[wb + hwoff0]) =
            (unsigned short)(packed & 0xffffu);
        *reinterpret_cast<unsigned short*>(&a_lds[wb + hwoff1]) =
            (unsigned short)(packed >> 16);
        // F: single raw barrier per step
        block_sync_lds();
    };

    for (int th = 0; th < T_STEPS / 2; ++th) {
        step(2 * th,     0,   BUF, xhA, xhB, xfA, xfB);
        step(2 * th + 1, BUF, 0,   xhB, xhA, xfB, xfA);
    }
    // h(T-1) is in buffer 0
    if (WRITE_H) {
        unsigned int hv = *reinterpret_cast<const unsigned int*>(&a_lds[hroff4]);
        *reinterpret_cast<unsigned int*>(
            &hbuf[(size_t)(T_STEPS - 1) * (BATCH * HID) + sgoff4]) = hv;
    }
    // fused final FC: out[b] = h_255[b] . Wfc + bfc
    if (FINAL && tid < 128) {
        const int r = tid >> 4, seg = tid & 15;
        float s = 0.f;
        #pragma unroll
        for (int k = 0; k < 8; ++k) {
            const int j = seg * 8 + k;
            s += bf2f(*reinterpret_cast<const unsigned short*>(&a_lds[lposR(r, 2 * j)]))
                 * Wfc[j];
        }
        #pragma unroll
        for (int off = 8; off >= 1; off >>= 1) s += __shfl_xor(s, off);
        if (seg == 0) out[b0 + r] = s + bfc[0];
    }
}

extern "C" void kernel_launch(void* const* d_in, const int* in_sizes, int n_in,
                              void* d_out, int out_size, void* d_ws, size_t ws_size,
                              hipStream_t stream) {
    (void)in_sizes; (void)n_in; (void)out_size; (void)ws_size;
    const float* x    = (const float*)d_in[0];
    const float* Wih0 = (const float*)d_in[1];
    const float* Whh0 = (const float*)d_in[2];
    const float* bih0 = (const float*)d_in[3];
    const float* bhh0 = (const float*)d_in[4];
    const float* Wih1 = (const float*)d_in[5];
    const float* Whh1 = (const float*)d_in[6];
    const float* bih1 = (const float*)d_in[7];
    const float* bhh1 = (const float*)d_in[8];
    const float* Wih2 = (const float*)d_in[9];
    const float* Whh2 = (const float*)d_in[10];
    const float* bih2 = (const float*)d_in[11];
    const float* bhh2 = (const float*)d_in[12];
    const float* Wfc  = (const float*)d_in[13];
    const float* bfc  = (const float*)d_in[14];
    float* out = (float*)d_out;
    unsigned short* hbuf = (unsigned short*)d_ws;   // [256][2048][128] bf16 = 134 MB

    dim3 grid(BATCH / ROWS), block(512);
    lstm_layer<true,  true,  false><<<grid, block, 0, stream>>>(x,       Wih0, Whh0, bih0, bhh0, hbuf, nullptr, nullptr, nullptr);
    lstm_layer<false, true,  false><<<grid, block, 0, stream>>>(nullptr, Wih1, Whh1, bih1, bhh1, hbuf, nullptr, nullptr, nullptr);
    lstm_layer<false, false, true ><<<grid, block, 0, stream>>>(nullptr, Wih2, Whh2, bih2, bhh2, hbuf, Wfc,     bfc,     out);
}

// Round 7
// 569.041 us; speedup vs baseline: 1.5865x; 1.5865x over previous
//
#include <hip/hip_runtime.h>

#define T_STEPS 256
#define BATCH   2048
#define HID     128
#define ROWS    8          // batch rows per block (grid = BATCH/ROWS = 256)

typedef short short8  __attribute__((ext_vector_type(8)));
typedef short short4v __attribute__((ext_vector_type(4)));
typedef float float4v __attribute__((ext_vector_type(4)));

template<bool B> struct BoolC { static constexpr bool value = B; };

__device__ __forceinline__ unsigned short f2bf(float f) {
    unsigned int u = __builtin_bit_cast(unsigned int, f);
    u += 0x7fffu + ((u >> 16) & 1u);
    return (unsigned short)(u >> 16);
}
__device__ __forceinline__ float bf2f(unsigned short b) {
    unsigned int u = ((unsigned int)b) << 16;
    return __builtin_bit_cast(float, u);
}

#if __has_builtin(__builtin_amdgcn_exp2f)
#define EXP2F(x) __builtin_amdgcn_exp2f(x)
#else
#define EXP2F(x) exp2f(x)
#endif
__device__ __forceinline__ float sigf(float x) {
    return __builtin_amdgcn_rcpf(1.0f + EXP2F(x * -1.442695041f));
}
__device__ __forceinline__ float tanh_fast(float x) {
    return 2.0f * __builtin_amdgcn_rcpf(1.0f + EXP2F(x * -2.885390082f)) - 1.0f;
}

// Raw barrier without the vmcnt(0) drain of __syncthreads().
__device__ __forceinline__ void block_sync_lds() {
    asm volatile("s_waitcnt lgkmcnt(0)" ::: "memory");
    __builtin_amdgcn_s_barrier();
    __builtin_amdgcn_sched_barrier(0);
}

// h buffer: [8 rows][256 B], XOR-swizzled, 16-B granule.
__device__ __forceinline__ int lposH(int row, int off) {
    return row * 256 + (off ^ ((row & 7) << 4));
}
// x tile (L1/2): [16 rows][256 B]
__device__ __forceinline__ int lposX(int row, int off) {
    return row * 256 + (off ^ ((row & 7) << 4));
}
// x tile (L0): [16 rows][64 B]
__device__ __forceinline__ int lposX0(int row, int off) {
    return row * 64 + (off ^ ((row & 3) << 4));
}

__device__ __forceinline__ short8 load_w8(const float* __restrict__ p) {
    float4v a = *reinterpret_cast<const float4v*>(p);
    float4v b = *reinterpret_cast<const float4v*>(p + 4);
    short8 r;
    r[0] = (short)f2bf(a[0]); r[1] = (short)f2bf(a[1]);
    r[2] = (short)f2bf(a[2]); r[3] = (short)f2bf(a[3]);
    r[4] = (short)f2bf(b[0]); r[5] = (short)f2bf(b[1]);
    r[6] = (short)f2bf(b[2]); r[7] = (short)f2bf(b[3]);
    return r;
}

// One LSTM layer. 512 thr (8 waves), 8 batch rows, grid 256 (1 block/CU).
// x-projection for steps {t+1,t+2} packed into ONE M=16 MFMA pass at odd
// steps (rows permuted so each thread's xg lands in its own acc regs:
// regs{0,1}=first step, regs{2,3}=second; no cross-lane traffic).
// h-MFMA A-rows alias-permuted so gates are always acc regs {0,1}.
template<bool IS_L0, bool WRITE_H, bool FINAL>
__global__ __launch_bounds__(512, 2)
void lstm_layer(const float* __restrict__ x0,
                const float* __restrict__ Wih,
                const float* __restrict__ Whh,
                const float* __restrict__ bih,
                const float* __restrict__ bhh,
                unsigned short* __restrict__ hbuf,   // [T][B][H] bf16
                const float* __restrict__ Wfc,
                const float* __restrict__ bfc,
                float* __restrict__ out)
{
    constexpr int XKS = IS_L0 ? 1 : 4;               // x K-slices per 2-step tile
    constexpr int XRB = IS_L0 ? 64 : 256;            // x-tile row bytes
    constexpr int HB  = ROWS * 256;                  // 2048 B per h buffer
    constexpr int XB  = 16 * XRB;                    // x slot bytes
    constexpr int LDS_TOT = 2 * HB + 2 * XB;
    __shared__ __attribute__((aligned(16))) unsigned char a_lds[LDS_TOT];
    const int XS0 = 2 * HB, XS1 = 2 * HB + XB;

    const int tid  = threadIdx.x;
    const int lane = tid & 63;
    const int wv   = tid >> 6;
    const int b0   = blockIdx.x * ROWS;

    const int t16   = lane & 15;
    const int kgrp8 = (lane >> 4) * 8;
    const int jcol  = 16 * wv + t16;                 // owned gate/h column
    const int row0  = ((lane >> 4) & 1) * 4 + ((lane >> 5) & 1) * 2;

    // h A-frag rows: permuted alias {0,1,0,1,4,5,4,5,2,3,2,3,6,7,6,7}[t16]
    const int g2   = t16 >> 2;
    const int hrow = ((g2 & 1) << 2) | ((g2 >> 1) << 1) | (t16 & 1);
    int aoffH[4];
    #pragma unroll
    for (int ks = 0; ks < 4; ++ks)
        aoffH[ks] = lposH(hrow, ks * 64 + kgrp8 * 2);
    // x A-frag rows: natural t16 (tile is row-permuted at staging)
    int aoffX[XKS];
    #pragma unroll
    for (int s = 0; s < XKS; ++s)
        aoffX[s] = IS_L0 ? lposX0(t16, kgrp8 * 2)
                         : lposX(t16, s * 64 + kgrp8 * 2);

    const int hwoff0 = lposH(row0,     2 * jcol);
    const int hwoff1 = lposH(row0 + 1, 2 * jcol);

    // h global-write map: 512 thr x 4 B cover 8 rows x 256 B
    const int srow4 = tid >> 6, scol4 = tid & 63;
    const int hroff4 = lposH(srow4, scol4 * 4);
    const size_t sgoff4 = (size_t)(b0 + srow4) * HID + scol4 * 2;  // shorts

    // x staging map (L1/2): 512 thr x 8 B cover 16 tile-rows x 256 B.
    // tile row ar holds x(t_base + s), batch row sb:  ar = (b&1)+2s+8*((b>>1)&1)+4*(b>>2)
    const int sar = tid >> 5, sc8 = tid & 31;
    const int sb  = (sar & 1) | (((sar >> 3) & 1) << 1) | (((sar >> 2) & 1) << 2);
    const int ss  = (sar >> 1) & 1;
    const int xwoff = lposX(sar, sc8 * 8);
    const size_t xgrow = (size_t)(b0 + sb) * HID + sc8 * 4;        // shorts
    // x staging map (L0): 384 thr x 1 float cover 16 tile-rows x 24
    const bool xvalid = tid < 384;
    const int ar0 = xvalid ? tid / 24 : 0, xc = xvalid ? tid % 24 : 0;
    const int xb_ = (ar0 & 1) | (((ar0 >> 3) & 1) << 1) | (((ar0 >> 2) & 1) << 2);
    const int xs  = (ar0 >> 1) & 1;
    const int xw0off = lposX0(ar0, xc * 2);
    const size_t x0row = (size_t)(b0 + xb_) * (T_STEPS * 24) + xc;

    // ---- weights -> registers ----
    short8 wfh[4][4], wfx[4][XKS];
    float  bias[4];
    #pragma unroll
    for (int q = 0; q < 4; ++q) {
        const int n = 128 * q + jcol;
        bias[q] = bih[n] + bhh[n];
        #pragma unroll
        for (int ks = 0; ks < 4; ++ks)
            wfh[q][ks] = load_w8(Whh + n * 128 + ks * 32 + kgrp8);
        if (IS_L0) {
            if (kgrp8 < 24) wfx[q][0] = load_w8(Wih + n * 24 + kgrp8);
            else            { short8 z = {0,0,0,0,0,0,0,0}; wfx[q][0] = z; }
        } else {
            #pragma unroll
            for (int s = 0; s < 4; ++s)
                wfx[q][s] = load_w8(Wih + n * 128 + s * 32 + kgrp8);
        }
    }

    // zero ALL LDS (h(-1)=0; L0 x pad cols stay 0 forever)
    {
        short8 z = {0,0,0,0,0,0,0,0};
        for (int i = tid * 16; i < LDS_TOT; i += 512 * 16)
            *reinterpret_cast<short8*>(&a_lds[i]) = z;
    }
    __syncthreads();

    // ---- prologue: stage slot0 = {x(0),x(1)}; regs <- {x(2),x(3)} ----
    short4v xpre = {0, 0, 0, 0};
    float   xpref = 0.f;
    if (!IS_L0) {
        short4v v = *reinterpret_cast<const short4v*>(
            &hbuf[(size_t)(0 + ss) * (BATCH * HID) + xgrow]);
        *reinterpret_cast<short4v*>(&a_lds[XS0 + xwoff]) = v;
        xpre = *reinterpret_cast<const short4v*>(
            &hbuf[(size_t)(2 + ss) * (BATCH * HID) + xgrow]);
    } else if (xvalid) {
        float v = x0[x0row + (size_t)(0 + xs) * 24];
        *reinterpret_cast<unsigned short*>(&a_lds[XS0 + xw0off]) = f2bf(v);
        xpref = x0[x0row + (size_t)(2 + xs) * 24];
    }
    __syncthreads();

    // prologue x-phase: xg{0,1}
    float4v xacc[4];
    #pragma unroll
    for (int q = 0; q < 4; ++q)
        xacc[q] = float4v{bias[q], bias[q], bias[q], bias[q]};
    {
        short8 xa[XKS];
        #pragma unroll
        for (int s = 0; s < XKS; ++s)
            xa[s] = *reinterpret_cast<const short8*>(&a_lds[XS0 + aoffX[s]]);
        #pragma unroll
        for (int s = 0; s < XKS; ++s)
            #pragma unroll
            for (int q = 0; q < 4; ++q)
                xacc[q] = __builtin_amdgcn_mfma_f32_16x16x32_bf16(xa[s], wfx[q][s], xacc[q], 0, 0, 0);
    }

    float creg[2] = {0.f, 0.f};

    auto do_step = [&](int t, auto ODDC) {
        constexpr bool ODD = decltype(ODDC)::value;
        const int rb = ODD ? HB : 0;
        const int wb = ODD ? 0 : HB;
        // h(t-1) global write (overlaps compute)
        if (WRITE_H && t > 0) {
            unsigned int hv = *reinterpret_cast<const unsigned int*>(&a_lds[rb + hroff4]);
            *reinterpret_cast<unsigned int*>(
                &hbuf[(size_t)(t - 1) * (BATCH * HID) + sgoff4]) = hv;
        }
        if constexpr (!ODD) {
            // stage x-tile {x(t+2),x(t+3)} into slot ((t>>1)&1)^1 from regs
            const int xsb = ((((t >> 1) & 1) ^ 1) ? XS1 : XS0);
            if (!IS_L0) {
                if (t + 2 + ss < T_STEPS)
                    *reinterpret_cast<short4v*>(&a_lds[xsb + xwoff]) = xpre;
            } else if (xvalid && (t + 2 + xs < T_STEPS))
                *reinterpret_cast<unsigned short*>(&a_lds[xsb + xw0off]) = f2bf(xpref);
        } else {
            // issue loads for the next staging: {x(t+3), x(t+4)}
            if (!IS_L0) {
                if (t + 3 + ss < T_STEPS)
                    xpre = *reinterpret_cast<const short4v*>(
                        &hbuf[(size_t)(t + 3 + ss) * (BATCH * HID) + xgrow]);
            } else if (xvalid && (t + 3 + xs < T_STEPS))
                xpref = x0[x0row + (size_t)(t + 3 + xs) * 24];
        }
        // acc init from pipelined xg (even: regs {0,1}; odd: regs {2,3})
        float4v acc[4];
        #pragma unroll
        for (int q = 0; q < 4; ++q) {
            const float a = ODD ? xacc[q][2] : xacc[q][0];
            const float b = ODD ? xacc[q][3] : xacc[q][1];
            acc[q] = float4v{a, b, a, b};
        }
        // h ds_reads + 4-deep h-MFMA chains (4 gates interleaved)
        short8 hva[4];
        #pragma unroll
        for (int ks = 0; ks < 4; ++ks)
            hva[ks] = *reinterpret_cast<const short8*>(&a_lds[rb + aoffH[ks]]);
        __builtin_amdgcn_s_setprio(1);
        #pragma unroll
        for (int ks = 0; ks < 4; ++ks)
            #pragma unroll
            for (int q = 0; q < 4; ++q)
                acc[q] = __builtin_amdgcn_mfma_f32_16x16x32_bf16(hva[ks], wfh[q][ks], acc[q], 0, 0, 0);
        // x-phase at odd steps: produce xg{t+1, t+2} (off critical path)
        if constexpr (ODD) {
            if (t + 1 < T_STEPS) {
                const int xrb_ = ((((t + 1) >> 1) & 1) ? XS1 : XS0);
                #pragma unroll
                for (int q = 0; q < 4; ++q)
                    xacc[q] = float4v{bias[q], bias[q], bias[q], bias[q]};
                short8 xa[XKS];
                #pragma unroll
                for (int s = 0; s < XKS; ++s)
                    xa[s] = *reinterpret_cast<const short8*>(&a_lds[xrb_ + aoffX[s]]);
                #pragma unroll
                for (int s = 0; s < XKS; ++s)
                    #pragma unroll
                    for (int q = 0; q < 4; ++q)
                        xacc[q] = __builtin_amdgcn_mfma_f32_16x16x32_bf16(xa[s], wfx[q][s], xacc[q], 0, 0, 0);
            }
        }
        __builtin_amdgcn_s_setprio(0);
        // cell update: gates are acc[q][0], acc[q][1] for every thread
        const float c0 = sigf(acc[1][0]) * creg[0] + sigf(acc[0][0]) * tanh_fast(acc[2][0]);
        const float c1 = sigf(acc[1][1]) * creg[1] + sigf(acc[0][1]) * tanh_fast(acc[2][1]);
        creg[0] = c0;  creg[1] = c1;
        const float h0 = sigf(acc[3][0]) * tanh_fast(c0);
        const float h1 = sigf(acc[3][1]) * tanh_fast(c1);
        unsigned int packed;
        asm("v_cvt_pk_bf16_f32 %0, %1, %2" : "=v"(packed) : "v"(h0), "v"(h1));
        *reinterpret_cast<unsigned short*>(&a_lds[wb + hwoff0]) =
            (unsigned short)(packed & 0xffffu);
        *reinterpret_cast<unsigned short*>(&a_lds[wb + hwoff1]) =
            (unsigned short)(packed >> 16);
        block_sync_lds();
    };

    for (int th = 0; th < T_STEPS / 2; ++th) {
        do_step(2 * th,     BoolC<false>{});
        do_step(2 * th + 1, BoolC<true>{});
    }
    // h(255) is in buffer 0
    if (WRITE_H) {
        unsigned int hv = *reinterpret_cast<const unsigned int*>(&a_lds[hroff4]);
        *reinterpret_cast<unsigned int*>(
            &hbuf[(size_t)(T_STEPS - 1) * (BATCH * HID) + sgoff4]) = hv;
    }
    // fused final FC: out[b] = h_255[b] . Wfc + bfc
    if (FINAL && tid < 128) {
        const int r = tid >> 4, seg = tid & 15;
        float s = 0.f;
        #pragma unroll
        for (int k = 0; k < 8; ++k) {
            const int j = seg * 8 + k;
            s += bf2f(*reinterpret_cast<const unsigned short*>(&a_lds[lposH(r, 2 * j)]))
                 * Wfc[j];
        }
        #pragma unroll
        for (int off = 8; off >= 1; off >>= 1) s += __shfl_xor(s, off);
        if (seg == 0) out[b0 + r] = s + bfc[0];
    }
}

extern "C" void kernel_launch(void* const* d_in, const int* in_sizes, int n_in,
                              void* d_out, int out_size, void* d_ws, size_t ws_size,
                              hipStream_t stream) {
    (void)in_sizes; (void)n_in; (void)out_size; (void)ws_size;
    const float* x    = (const float*)d_in[0];
    const float* Wih0 = (const float*)d_in[1];
    const float* Whh0 = (const float*)d_in[2];
    const float* bih0 = (const float*)d_in[3];
    const float* bhh0 = (const float*)d_in[4];
    const float* Wih1 = (const float*)d_in[5];
    const float* Whh1 = (const float*)d_in[6];
    const float* bih1 = (const float*)d_in[7];
    const float* bhh1 = (const float*)d_in[8];
    const float* Wih2 = (const float*)d_in[9];
    const float* Whh2 = (const float*)d_in[10];
    const float* bih2 = (const float*)d_in[11];
    const float* bhh2 = (const float*)d_in[12];
    const float* Wfc  = (const float*)d_in[13];
    const float* bfc  = (const float*)d_in[14];
    float* out = (float*)d_out;
    unsigned short* hbuf = (unsigned short*)d_ws;   // [256][2048][128] bf16 = 134 MB

    dim3 grid(BATCH / ROWS), block(512);
    lstm_layer<true,  true,  false><<<grid, block, 0, stream>>>(x,       Wih0, Whh0, bih0, bhh0, hbuf, nullptr, nullptr, nullptr);
    lstm_layer<false, true,  false><<<grid, block, 0, stream>>>(nullptr, Wih1, Whh1, bih1, bhh1, hbuf, nullptr, nullptr, nullptr);
    lstm_layer<false, false, true ><<<grid, block, 0, stream>>>(nullptr, Wih2, Whh2, bih2, bhh2, hbuf, Wfc,     bfc,     out);
}